// Round 9
// baseline (299.114 us; speedup 1.0000x reference)
//
#include <hip/hip_runtime.h>
#include <hip/hip_fp16.h>

#define SEQ    128
#define NITER  (SEQ+8)           /* 9-deep pipeline, 1 step per barrier iteration */
#define NTL    512               /* n-tiles of 16; one block per tile */
#define TOT    (SEQ*8192)        /* 1048576 */
#define T3     (TOT*3)

typedef __attribute__((ext_vector_type(8))) _Float16 half8;
typedef __attribute__((ext_vector_type(4))) float    f32x4;
union H8 { half8 v; ushort s[8]; uint u[4]; };

__device__ __forceinline__ float siluf(float x){ return x*__builtin_amdgcn_rcpf(1.f+__expf(-x)); }
__device__ __forceinline__ ushort f2h(float x){ _Float16 h=(_Float16)x; return __builtin_bit_cast(ushort,h); }
__device__ __forceinline__ float  h2fl(ushort u){ _Float16 h=__builtin_bit_cast(_Float16,u); return (float)h; }
__device__ __forceinline__ float  lo16(uint u){ return h2fl((ushort)(u&0xFFFFu)); }
__device__ __forceinline__ float  hi16(uint u){ return h2fl((ushort)(u>>16)); }
__device__ __forceinline__ uint   pkf(float a, float b){ auto r=__builtin_amdgcn_cvt_pkrtz(a,b); return __builtin_bit_cast(uint,r); }

// RAW pipeline barrier: LDS-only ordering (lgkmcnt); vmcnt floats. Validated R1.
__device__ __forceinline__ void pipe_barrier(){
    __builtin_amdgcn_sched_barrier(0);
    asm volatile("s_waitcnt lgkmcnt(0)" ::: "memory");
    __builtin_amdgcn_s_barrier();
    __builtin_amdgcn_sched_barrier(0);
}

// K-slot permutation: k-slot 8g+j holds unit 4j+g (j<5); bias at k-slot 5 (g=0,j=5).
__device__ __forceinline__ half8 packB(int q, float v0,float v1,float v2,float v3,float v4,float vb){
    H8 o;
    o.u[0]=pkf(v0,v1);
    o.u[1]=pkf(v2,v3);
    o.u[2]=pkf(v4, (q==0)? vb : 0.f);
    o.u[3]=0u;
    return o.v;
}

// gates pre-scaled by -1/ln2 (-2/ln2 for g row). 5 exp + 3 rcp (R6-validated).
__device__ __forceinline__ float gate_step(const f32x4 a, float& c){
    const float ei=__builtin_amdgcn_exp2f(a[0]);
    const float ef=__builtin_amdgcn_exp2f(a[1]);
    const float eg=__builtin_amdgcn_exp2f(a[2]);
    const float eo=__builtin_amdgcn_exp2f(a[3]);
    const float rf =__builtin_amdgcn_rcpf(1.f+ef);
    const float rig=__builtin_amdgcn_rcpf((1.f+ei)*(1.f+eg));
    c = c*rf + (1.f-eg)*rig;
    const float ec=__builtin_amdgcn_exp2f(fminf(-2.885390082f*c,60.f));
    const float roc=__builtin_amdgcn_rcpf((1.f+eo)*(1.f+ec));
    return (1.f-ec)*roc;
}

__device__ __forceinline__ void red4(float& s, float& ss){
    s  += __shfl_xor(s,16,64);  s  += __shfl_xor(s,32,64);
    ss += __shfl_xor(ss,16,64); ss += __shfl_xor(ss,32,64);
}

// 20-row GEMV tile row->unit maps
__device__ __forceinline__ int uemap(int tt, int m){
    if (tt==0) return 4*(m&3)+(m>>2);
    return ((m&3)==0) ? 16+(m>>2) : -1;
}

// ---------------------------------------------------------------- single fused kernel
// 512 blocks x 10 waves (640 thr), one n-tile, ONE step per barrier iteration.
// Fine-grained role pipeline for SIMD issue balance (all roles ~280-450 cy/step):
//   PREa(s=i)   : input+lin1+silu+LN1 -> yf frag
//   PREb(s=i-1) : lin2 MFMA+silu+LN2 -> preF/preX
//   L1a (s=i-2) : LSTM1 tiles 0-2 (6 MFMA + 3 gates) -> partials
//   L1b (s=i-2) : LSTM1 tiles 3-4 (4 MFMA + 2 gates) + x3-LN assembly(s-1)
//   L2a (s=i-4) : LSTM2 tiles 0-2 -> x4 partials
//   L2b (s=i-4) : LSTM2 tiles 3-4 -> x4 partials
//   P1  (s=i-5) : LN4+lin3+silu -> hh
//   P2  (s=i-6) : LN5+lin4+silu+residual -> xp
//   P3  (s=i-7) : LN6+lin5+silu -> fh frag
//   P4  (s=i-8) : heads MFMA + softmax/exp + stores
// h1f/h2f re-assembled locally by each LSTM wave from partner partials (recurrence
// advances 1 step/iter). Wave->SIMD (wv%4) placement balances per-SIMD issue:
//   S0{P1,P3,PREa} S1{P2,P4,L2a} S2{PREb,L2b} S3{L1a,L1b}.
// 2 blocks/CU co-resident -> 20 waves/CU (5/SIMD).
__global__ __launch_bounds__(640, 5) void k_all(
    const float* __restrict__ xlni, const float* __restrict__ imean, const float* __restrict__ istd,
    const float* __restrict__ w1,  const float* __restrict__ b1,  const float* __restrict__ g1,
    const float* __restrict__ w2,  const float* __restrict__ b2,  const float* __restrict__ g2,
    const float* __restrict__ wih1, const float* __restrict__ whh1,
    const float* __restrict__ bih1, const float* __restrict__ bhh1,
    const float* __restrict__ ln3g, const float* __restrict__ ln3b,
    const float* __restrict__ wih2, const float* __restrict__ whh2,
    const float* __restrict__ bih2, const float* __restrict__ bhh2,
    const float* __restrict__ g4, const float* __restrict__ w3, const float* __restrict__ b3,
    const float* __restrict__ g5, const float* __restrict__ w4, const float* __restrict__ b4,
    const float* __restrict__ g6, const float* __restrict__ w5, const float* __restrict__ b5,
    const float* __restrict__ wfw, const float* __restrict__ wfb,
    const float* __restrict__ sfw, const float* __restrict__ sfb,
    const float* __restrict__ dfw, const float* __restrict__ dfb,
    float* __restrict__ out)
{
    // handoff slots; depth chosen per producer->consumer gap (hazard-audited)
    __shared__ uint2  yfA[2][64];   __shared__ uint   yfB[2][64];
    __shared__ uint2  preFA[2][64]; __shared__ uint   preFB[2][64];
    __shared__ uint2  preXa[2][64]; __shared__ uint   preXb[2][64];
    __shared__ uint2  h1pA[2][64];  __shared__ uint   h1pB[2][64];
    __shared__ float2 sm1[2][64];
    __shared__ uint2  x3pA[4][64];  __shared__ uint   x3pB[4][64];
    __shared__ uint2  x3FA[2][64];  __shared__ uint   x3FB[2][64];
    __shared__ uint2  h2pA[2][64];  __shared__ uint   h2pB[2][64];
    __shared__ uint2  x4pA[4][64];  __shared__ uint   x4pB[4][64];
    __shared__ uint2  hhA[2][64];   __shared__ uint   hhB[2][64];
    __shared__ uint2  xpA[2][64];   __shared__ uint   xpB[2][64];
    __shared__ uint2  fhA[2][64];   __shared__ uint   fhB[2][64];

    const int tid  = threadIdx.x;
    const int wv   = tid >> 6;
    const int lane = tid & 63;
    const int col  = lane & 15, q = lane >> 4;
    const int nt   = blockIdx.x;
    const f32x4 Z  = {0.f,0.f,0.f,0.f};

    if (wv == 8){
        // ================= PREa: input + lin1 + silu + LN1 =================
        float wd[5], wu[5], ws0[5], ws1[5], ws2[5], ws3[5];
#pragma unroll
        for (int t=0;t<5;t++){
            const int u = 4*t+q;
            wd[t]=w1[u*6+0]; wu[t]=w1[u*6+1];
            ws0[t]=w1[u*6+2]+b1[u]; ws1[t]=w1[u*6+3]+b1[u];
            ws2[t]=w1[u*6+4]+b1[u]; ws3[t]=w1[u*6+5]+b1[u];
        }
        const float mu0=imean[0], mu1=imean[1];
        const float ri0=1.f/istd[0], ri1=1.f/istd[1];

        float cd0,cd1,crr, nd0,nd1,nrr;
        {
            const size_t i0 = ((size_t)0*8192 + (size_t)nt*16 + col)*3;
            cd0=xlni[i0]; cd1=xlni[i0+1]; crr=xlni[i0+2];
            const size_t i1 = ((size_t)1*8192 + (size_t)nt*16 + col)*3;
            nd0=xlni[i1]; nd1=xlni[i1+1]; nrr=xlni[i1+2];
        }
#pragma unroll 1
        for (int i=0;i<NITER;i++){
            if (i<SEQ){
                const int s=i;
                const float D0=cd0, D1=cd1, RR=crr;
                cd0=nd0; cd1=nd1; crr=nrr;
                { int st=s+2; st=(st<SEQ)?st:SEQ-1;
                  const size_t ib=((size_t)st*8192+(size_t)nt*16+col)*3;
                  nd0=xlni[ib]; nd1=xlni[ib+1]; nrr=xlni[ib+2]; }
                const float xd=(__logf(1e-5f+D0)-mu0)*ri0;
                const float xu=(__logf(fminf(fmaxf(D1,100.f),60000.f))-mu1)*ri1;
                int r=(int)fmaxf(RR,1.f)-1; r=r<0?0:(r>3?3:r);
                float av[5], s1=0.f, s2=0.f;
#pragma unroll
                for (int t=0;t<5;t++){
                    const float wsel=(r==0)?ws0[t]:(r==1)?ws1[t]:(r==2)?ws2[t]:ws3[t];
                    const float v = wd[t]*xd + wu[t]*xu + wsel;
                    av[t]=siluf(v); s1+=av[t]; s2+=av[t]*av[t];
                }
                red4(s1,s2);
                const float mn=s1*0.05f; float var=fmaxf(s2*0.05f-mn*mn,0.f);
                const float rs=__builtin_amdgcn_rsqf(var+1e-5f), mr=mn*rs;
                const half8 yf = packB(q, av[0]*rs-mr, av[1]*rs-mr, av[2]*rs-mr, av[3]*rs-mr, av[4]*rs-mr, 1.0f);
                H8 fo; fo.v=yf;
                yfA[s&1][lane]=make_uint2(fo.u[0],fo.u[1]); yfB[s&1][lane]=fo.u[2];
            }
            pipe_barrier();
        }
    } else if (wv == 2){
        // ================= PREb: lin2 MFMA + silu + LN2 =================
        half8 Aw2[2];
#pragma unroll
        for (int tt=0;tt<2;tt++){
            const int u = uemap(tt, col);
            H8 a;
#pragma unroll
            for (int j=0;j<8;j++){
                float v=0.f;
                if (u>=0){
                    if (j<5){ const int un=4*j+q; v = w2[u*20+un]*g1[un]; }
                    else if (j==5 && q==0) v = b2[u];
                }
                a.s[j]=f2h(v);
            }
            Aw2[tt]=a.v;
        }
#pragma unroll 1
        for (int i=0;i<NITER;i++){
            if (i>=1 && i<SEQ+1){
                const int s=i-1;
                const uint2 fa=yfA[s&1][lane]; const uint fb=yfB[s&1][lane];
                H8 fi; fi.u[0]=fa.x; fi.u[1]=fa.y; fi.u[2]=fb; fi.u[3]=0u;
                const f32x4 c0 = __builtin_amdgcn_mfma_f32_16x16x32_f16(Aw2[0], fi.v, Z, 0,0,0);
                const f32x4 c1 = __builtin_amdgcn_mfma_f32_16x16x32_f16(Aw2[1], fi.v, Z, 0,0,0);
                float X2[5], s1=0.f, s2=0.f;
#pragma unroll
                for (int t=0;t<5;t++){
                    const float v=siluf(t<4?c0[t]:c1[0]);
                    X2[t]=v; s1+=v; s2+=v*v;
                }
                red4(s1,s2);
                const float mn=s1*0.05f; float var=fmaxf(s2*0.05f-mn*mn,0.f);
                const float rs=__builtin_amdgcn_rsqf(var+1e-5f), mr=mn*rs;
                const half8 xnf = packB(q, X2[0]*rs-mr, X2[1]*rs-mr, X2[2]*rs-mr, X2[3]*rs-mr, X2[4]*rs-mr, 1.0f);
                H8 fo; fo.v=xnf;
                preFA[s&1][lane]=make_uint2(fo.u[0],fo.u[1]); preFB[s&1][lane]=fo.u[2];
                preXa[s&1][lane]=make_uint2(pkf(X2[0],X2[1]), pkf(X2[2],X2[3]));
                preXb[s&1][lane]=pkf(X2[4],0.f);
            }
            pipe_barrier();
        }
    } else if (wv == 3){
        // ================= L1a: LSTM1 tiles 0-2 =================
        half8 Aih[3], Ahh[3];
#pragma unroll
        for (int t=0;t<3;t++){
            const int M = t*16 + col, u = M>>2, g = M&3, r = g*20+u;
            const float sc = (g==2)? -2.885390082f : -1.442695041f;
            H8 a0,a1;
#pragma unroll
            for (int j=0;j<8;j++){
                float vih=0.f, vhh=0.f;
                if (j<5){
                    const int un = 4*j+q;
                    vih = wih1[r*20+un]*g2[un]*sc;
                    vhh = whh1[r*20+un]*sc;
                } else if (j==5 && q==0){
                    vih = (bih1[r]+bhh1[r])*sc;
                }
                a0.s[j]=f2h(vih); a1.s[j]=f2h(vhh);
            }
            Aih[t]=a0.v; Ahh[t]=a1.v;
        }
        float cg[3]={0,0,0};
        float h0=0.f,h1=0.f,h2=0.f;
#pragma unroll 1
        for (int i=0;i<NITER;i++){
            if (i>=2 && i<SEQ+2){
                const int s=i-2;
                half8 h1f;
                if (s==0){ H8 z; z.u[0]=0;z.u[1]=0;z.u[2]=0;z.u[3]=0; h1f=z.v; }
                else {
                    const uint w = h1pB[(s-1)&1][lane];
                    const float h3=lo16(w), h4=hi16(w);
                    H8 hf; hf.u[0]=pkf(h0,h1); hf.u[1]=pkf(h2,h3); hf.u[2]=pkf(h4,0.f); hf.u[3]=0u; h1f=hf.v;
                }
                const uint2 fa=preFA[s&1][lane]; const uint fb=preFB[s&1][lane];
                H8 fi; fi.u[0]=fa.x; fi.u[1]=fa.y; fi.u[2]=fb; fi.u[3]=0u;
                const uint2 xa=preXa[s&1][lane];
                const float x2r[3] = { lo16(xa.x), hi16(xa.x), lo16(xa.y) };
                float x3v[3], hn[3], sA=0.f, ssA=0.f;
#pragma unroll
                for (int t=0;t<3;t++){
                    f32x4 ac = __builtin_amdgcn_mfma_f32_16x16x32_f16(Aih[t], fi.v, Z, 0,0,0);
                    ac = __builtin_amdgcn_mfma_f32_16x16x32_f16(Ahh[t], h1f, ac, 0,0,0);
                    hn[t]=gate_step(ac, cg[t]);
                    x3v[t]=x2r[t]+hn[t]; sA+=x3v[t]; ssA+=x3v[t]*x3v[t];
                }
                h0=hn[0]; h1=hn[1]; h2=hn[2];
                h1pA[s&1][lane]=make_uint2(pkf(h0,h1), pkf(h2,0.f));
                sm1[s&1][lane]=make_float2(sA,ssA);
                x3pA[s&3][lane]=make_uint2(pkf(x3v[0],x3v[1]), pkf(x3v[2],0.f));
            }
            pipe_barrier();
        }
    } else if (wv == 7){
        // ================= L1b: LSTM1 tiles 3-4 + x3-LN assembly =================
        half8 Aih[2], Ahh[2];
#pragma unroll
        for (int tt=0;tt<2;tt++){
            const int t=3+tt;
            const int M = t*16 + col, u = M>>2, g = M&3, r = g*20+u;
            const float sc = (g==2)? -2.885390082f : -1.442695041f;
            H8 a0,a1;
#pragma unroll
            for (int j=0;j<8;j++){
                float vih=0.f, vhh=0.f;
                if (j<5){
                    const int un = 4*j+q;
                    vih = wih1[r*20+un]*g2[un]*sc;
                    vhh = whh1[r*20+un]*sc;
                } else if (j==5 && q==0){
                    vih = (bih1[r]+bhh1[r])*sc;
                }
                a0.s[j]=f2h(vih); a1.s[j]=f2h(vhh);
            }
            Aih[tt]=a0.v; Ahh[tt]=a1.v;
        }
        float cg[2]={0,0};
        float h3=0.f,h4=0.f, x3v3=0.f,x3v4=0.f, sB=0.f,ssB=0.f;
#pragma unroll 1
        for (int i=0;i<NITER;i++){
            // x3F assembly for step sg=i-3 (uses PREVIOUS iteration's regs/partials)
            if (i>=3 && i<SEQ+3){
                const int sg=i-3;
                const uint2 xa=x3pA[sg&3][lane];
                const float v0=lo16(xa.x), v1=hi16(xa.x), v2=lo16(xa.y);
                const float2 sm=sm1[sg&1][lane];
                float s1=sm.x+sB, s2=sm.y+ssB;
                red4(s1,s2);
                const float mn=s1*0.05f; float var=fmaxf(s2*0.05f-mn*mn,0.f);
                const float rs=__builtin_amdgcn_rsqf(var+1e-5f), mr=mn*rs;
                const half8 x3f = packB(q, v0*rs-mr, v1*rs-mr, v2*rs-mr, x3v3*rs-mr, x3v4*rs-mr, 1.0f);
                H8 fo; fo.v=x3f;
                x3FA[sg&1][lane]=make_uint2(fo.u[0],fo.u[1]); x3FB[sg&1][lane]=fo.u[2];
            }
            if (i>=2 && i<SEQ+2){
                const int s=i-2;
                half8 h1f;
                if (s==0){ H8 z; z.u[0]=0;z.u[1]=0;z.u[2]=0;z.u[3]=0; h1f=z.v; }
                else {
                    const uint2 w = h1pA[(s-1)&1][lane];
                    const float a0=lo16(w.x), a1=hi16(w.x), a2=lo16(w.y);
                    H8 hf; hf.u[0]=pkf(a0,a1); hf.u[1]=pkf(a2,h3); hf.u[2]=pkf(h4,0.f); hf.u[3]=0u; h1f=hf.v;
                }
                const uint2 fa=preFA[s&1][lane]; const uint fb=preFB[s&1][lane];
                H8 fi; fi.u[0]=fa.x; fi.u[1]=fa.y; fi.u[2]=fb; fi.u[3]=0u;
                const uint2 xa=preXa[s&1][lane]; const uint xb=preXb[s&1][lane];
                const float x2r[2] = { hi16(xa.y), lo16(xb) };
                float hn[2];
#pragma unroll
                for (int tt=0;tt<2;tt++){
                    f32x4 ac = __builtin_amdgcn_mfma_f32_16x16x32_f16(Aih[tt], fi.v, Z, 0,0,0);
                    ac = __builtin_amdgcn_mfma_f32_16x16x32_f16(Ahh[tt], h1f, ac, 0,0,0);
                    hn[tt]=gate_step(ac, cg[tt]);
                }
                h3=hn[0]; h4=hn[1];
                x3v3=x2r[0]+h3; x3v4=x2r[1]+h4;
                sB=x3v3+x3v4; ssB=x3v3*x3v3+x3v4*x3v4;
                h1pB[s&1][lane]=pkf(h3,h4);
                x3pB[s&3][lane]=pkf(x3v3,x3v4);
            }
            pipe_barrier();
        }
    } else if (wv == 9){
        // ================= L2a: LSTM2 tiles 0-2 =================
        half8 Aih[3], Ahh[3];
#pragma unroll
        for (int t=0;t<3;t++){
            const int M = t*16 + col, u = M>>2, g = M&3, r = g*20+u;
            const float sc = (g==2)? -2.885390082f : -1.442695041f;
            H8 a0,a1;
#pragma unroll
            for (int j=0;j<8;j++){
                float vih=0.f, vhh=0.f;
                if (j<5){
                    const int un = 4*j+q;
                    vih = wih2[r*20+un]*ln3g[un]*sc;
                    vhh = whh2[r*20+un]*sc;
                } else if (j==5 && q==0){
                    float b2s = bih2[r]+bhh2[r];
                    for (int kk=0;kk<20;kk++) b2s += wih2[r*20+kk]*ln3b[kk];
                    vih = b2s*sc;
                }
                a0.s[j]=f2h(vih); a1.s[j]=f2h(vhh);
            }
            Aih[t]=a0.v; Ahh[t]=a1.v;
        }
        float cg[3]={0,0,0};
        float h0=0.f,h1=0.f,h2=0.f;
#pragma unroll 1
        for (int i=0;i<NITER;i++){
            if (i>=4 && i<SEQ+4){
                const int s=i-4;
                half8 h2f;
                if (s==0){ H8 z; z.u[0]=0;z.u[1]=0;z.u[2]=0;z.u[3]=0; h2f=z.v; }
                else {
                    const uint w = h2pB[(s-1)&1][lane];
                    const float h3=lo16(w), h4=hi16(w);
                    H8 hf; hf.u[0]=pkf(h0,h1); hf.u[1]=pkf(h2,h3); hf.u[2]=pkf(h4,0.f); hf.u[3]=0u; h2f=hf.v;
                }
                const uint2 fa=x3FA[s&1][lane]; const uint fb=x3FB[s&1][lane];
                H8 fi; fi.u[0]=fa.x; fi.u[1]=fa.y; fi.u[2]=fb; fi.u[3]=0u;
                const uint2 xa=x3pA[s&3][lane];
                const float x3r[3] = { lo16(xa.x), hi16(xa.x), lo16(xa.y) };
                float x4v[3], hn[3];
#pragma unroll
                for (int t=0;t<3;t++){
                    f32x4 ac = __builtin_amdgcn_mfma_f32_16x16x32_f16(Aih[t], fi.v, Z, 0,0,0);
                    ac = __builtin_amdgcn_mfma_f32_16x16x32_f16(Ahh[t], h2f, ac, 0,0,0);
                    hn[t]=gate_step(ac, cg[t]);
                    x4v[t]=x3r[t]+hn[t];
                }
                h0=hn[0]; h1=hn[1]; h2=hn[2];
                h2pA[s&1][lane]=make_uint2(pkf(h0,h1), pkf(h2,0.f));
                x4pA[s&3][lane]=make_uint2(pkf(x4v[0],x4v[1]), pkf(x4v[2],0.f));
            }
            pipe_barrier();
        }
    } else if (wv == 6){
        // ================= L2b: LSTM2 tiles 3-4 =================
        half8 Aih[2], Ahh[2];
#pragma unroll
        for (int tt=0;tt<2;tt++){
            const int t=3+tt;
            const int M = t*16 + col, u = M>>2, g = M&3, r = g*20+u;
            const float sc = (g==2)? -2.885390082f : -1.442695041f;
            H8 a0,a1;
#pragma unroll
            for (int j=0;j<8;j++){
                float vih=0.f, vhh=0.f;
                if (j<5){
                    const int un = 4*j+q;
                    vih = wih2[r*20+un]*ln3g[un]*sc;
                    vhh = whh2[r*20+un]*sc;
                } else if (j==5 && q==0){
                    float b2s = bih2[r]+bhh2[r];
                    for (int kk=0;kk<20;kk++) b2s += wih2[r*20+kk]*ln3b[kk];
                    vih = b2s*sc;
                }
                a0.s[j]=f2h(vih); a1.s[j]=f2h(vhh);
            }
            Aih[tt]=a0.v; Ahh[tt]=a1.v;
        }
        float cg[2]={0,0};
        float h3=0.f,h4=0.f;
#pragma unroll 1
        for (int i=0;i<NITER;i++){
            if (i>=4 && i<SEQ+4){
                const int s=i-4;
                half8 h2f;
                if (s==0){ H8 z; z.u[0]=0;z.u[1]=0;z.u[2]=0;z.u[3]=0; h2f=z.v; }
                else {
                    const uint2 w = h2pA[(s-1)&1][lane];
                    const float a0=lo16(w.x), a1=hi16(w.x), a2=lo16(w.y);
                    H8 hf; hf.u[0]=pkf(a0,a1); hf.u[1]=pkf(a2,h3); hf.u[2]=pkf(h4,0.f); hf.u[3]=0u; h2f=hf.v;
                }
                const uint2 fa=x3FA[s&1][lane]; const uint fb=x3FB[s&1][lane];
                H8 fi; fi.u[0]=fa.x; fi.u[1]=fa.y; fi.u[2]=fb; fi.u[3]=0u;
                const uint xb=x3pB[s&3][lane];
                const float x3r[2] = { lo16(xb), hi16(xb) };
                float hn[2];
#pragma unroll
                for (int tt=0;tt<2;tt++){
                    f32x4 ac = __builtin_amdgcn_mfma_f32_16x16x32_f16(Aih[tt], fi.v, Z, 0,0,0);
                    ac = __builtin_amdgcn_mfma_f32_16x16x32_f16(Ahh[tt], h2f, ac, 0,0,0);
                    hn[tt]=gate_step(ac, cg[tt]);
                }
                h3=hn[0]; h4=hn[1];
                const float x4_3=x3r[0]+h3, x4_4=x3r[1]+h4;
                h2pB[s&1][lane]=pkf(h3,h4);
                x4pB[s&3][lane]=pkf(x4_3,x4_4);
            }
            pipe_barrier();
        }
    } else if (wv == 0){
        // ================= P1: LN4 + lin3 + silu =================
        half8 A3[2];
#pragma unroll
        for (int tt=0;tt<2;tt++){
            const int u = uemap(tt, col);
            H8 a;
#pragma unroll
            for (int j=0;j<8;j++){
                float v=0.f;
                if (u>=0){
                    if (j<5){ const int un=4*j+q; v=w3[u*20+un]*g4[un]; }
                    else if (j==5 && q==0) v=b3[u];
                }
                a.s[j]=f2h(v);
            }
            A3[tt]=a.v;
        }
#pragma unroll 1
        for (int i=0;i<NITER;i++){
            if (i>=5 && i<SEQ+5){
                const int s=i-5;
                const uint2 pa=x4pA[s&3][lane]; const uint pb=x4pB[s&3][lane];
                float x4[5] = { lo16(pa.x), hi16(pa.x), lo16(pa.y), lo16(pb), hi16(pb) };
                float s1=0.f, s2=0.f;
#pragma unroll
                for (int t=0;t<5;t++){ s1+=x4[t]; s2+=x4[t]*x4[t]; }
                red4(s1,s2);
                const float mn=s1*0.05f; float var=fmaxf(s2*0.05f-mn*mn,0.f);
                const float rs=__builtin_amdgcn_rsqf(var+1e-5f), mr=mn*rs;
                const half8 f4 = packB(q, x4[0]*rs-mr, x4[1]*rs-mr, x4[2]*rs-mr, x4[3]*rs-mr, x4[4]*rs-mr, 1.0f);
                const f32x4 c0 = __builtin_amdgcn_mfma_f32_16x16x32_f16(A3[0], f4, Z, 0,0,0);
                const f32x4 c1 = __builtin_amdgcn_mfma_f32_16x16x32_f16(A3[1], f4, Z, 0,0,0);
                float hh[5];
#pragma unroll
                for (int t=0;t<5;t++) hh[t]=siluf(t<4?c0[t]:c1[0]);
                hhA[s&1][lane]=make_uint2(pkf(hh[0],hh[1]), pkf(hh[2],hh[3]));
                hhB[s&1][lane]=pkf(hh[4],0.f);
            }
            pipe_barrier();
        }
    } else if (wv == 1){
        // ================= P2: LN5 + lin4 + silu + residual =================
        half8 A4[2];
#pragma unroll
        for (int tt=0;tt<2;tt++){
            const int u = uemap(tt, col);
            H8 a;
#pragma unroll
            for (int j=0;j<8;j++){
                float v=0.f;
                if (u>=0){
                    if (j<5){ const int un=4*j+q; v=w4[u*20+un]*g5[un]; }
                    else if (j==5 && q==0) v=b4[u];
                }
                a.s[j]=f2h(v);
            }
            A4[tt]=a.v;
        }
#pragma unroll 1
        for (int i=0;i<NITER;i++){
            if (i>=6 && i<SEQ+6){
                const int s=i-6;
                const uint2 ha=hhA[s&1][lane]; const uint hb=hhB[s&1][lane];
                float hh[5] = { lo16(ha.x), hi16(ha.x), lo16(ha.y), hi16(ha.y), lo16(hb) };
                float s1=0.f, s2=0.f;
#pragma unroll
                for (int t=0;t<5;t++){ s1+=hh[t]; s2+=hh[t]*hh[t]; }
                red4(s1,s2);
                const float mn=s1*0.05f; float var=fmaxf(s2*0.05f-mn*mn,0.f);
                const float rs=__builtin_amdgcn_rsqf(var+1e-5f), mr=mn*rs;
                const half8 f5 = packB(q, hh[0]*rs-mr, hh[1]*rs-mr, hh[2]*rs-mr, hh[3]*rs-mr, hh[4]*rs-mr, 1.0f);
                const f32x4 c0 = __builtin_amdgcn_mfma_f32_16x16x32_f16(A4[0], f5, Z, 0,0,0);
                const f32x4 c1 = __builtin_amdgcn_mfma_f32_16x16x32_f16(A4[1], f5, Z, 0,0,0);
                const uint2 pa=x4pA[s&3][lane]; const uint pb=x4pB[s&3][lane];
                const float x4[5] = { lo16(pa.x), hi16(pa.x), lo16(pa.y), lo16(pb), hi16(pb) };
                float xp[5];
#pragma unroll
                for (int t=0;t<5;t++) xp[t]=x4[t]+siluf(t<4?c0[t]:c1[0]);
                xpA[s&1][lane]=make_uint2(pkf(xp[0],xp[1]), pkf(xp[2],xp[3]));
                xpB[s&1][lane]=pkf(xp[4],0.f);
            }
            pipe_barrier();
        }
    } else if (wv == 4){
        // ================= P3: LN6 + lin5 + silu =================
        half8 A5[2];
#pragma unroll
        for (int tt=0;tt<2;tt++){
            const int u = uemap(tt, col);
            H8 a;
#pragma unroll
            for (int j=0;j<8;j++){
                float v=0.f;
                if (u>=0){
                    if (j<5){ const int un=4*j+q; v=w5[u*20+un]*g6[un]; }
                    else if (j==5 && q==0) v=b5[u];
                }
                a.s[j]=f2h(v);
            }
            A5[tt]=a.v;
        }
#pragma unroll 1
        for (int i=0;i<NITER;i++){
            if (i>=7 && i<SEQ+7){
                const int s=i-7;
                const uint2 xa=xpA[s&1][lane]; const uint xb=xpB[s&1][lane];
                float xp[5] = { lo16(xa.x), hi16(xa.x), lo16(xa.y), hi16(xa.y), lo16(xb) };
                float s1=0.f, s2=0.f;
#pragma unroll
                for (int t=0;t<5;t++){ s1+=xp[t]; s2+=xp[t]*xp[t]; }
                red4(s1,s2);
                const float mn=s1*0.05f; float var=fmaxf(s2*0.05f-mn*mn,0.f);
                const float rs=__builtin_amdgcn_rsqf(var+1e-5f), mr=mn*rs;
                const half8 f6 = packB(q, xp[0]*rs-mr, xp[1]*rs-mr, xp[2]*rs-mr, xp[3]*rs-mr, xp[4]*rs-mr, 1.0f);
                const f32x4 c0 = __builtin_amdgcn_mfma_f32_16x16x32_f16(A5[0], f6, Z, 0,0,0);
                const f32x4 c1 = __builtin_amdgcn_mfma_f32_16x16x32_f16(A5[1], f6, Z, 0,0,0);
                float xfv[5];
#pragma unroll
                for (int t=0;t<5;t++) xfv[t]=siluf(t<4?c0[t]:c1[0]);
                const half8 fh = packB(q, xfv[0],xfv[1],xfv[2],xfv[3],xfv[4], 1.0f);
                H8 fo; fo.v=fh;
                fhA[s&1][lane]=make_uint2(fo.u[0],fo.u[1]); fhB[s&1][lane]=fo.u[2];
            }
            pipe_barrier();
        }
    } else {
        // ================= P4 (wv==5): heads MFMA + softmax/exp + stores =================
        half8 Ahd;
        {
            const int m=col, hd=m>>2, jh=m&3;
            const float* Wp = (hd==0)? wfw : (hd==1)? sfw : dfw;
            const float* Bp = (hd==0)? wfb : (hd==1)? sfb : dfb;
            const bool ok = (hd<3)&&(jh<3);
            H8 a;
#pragma unroll
            for (int j=0;j<8;j++){
                float v=0.f;
                if (ok){
                    if (j<5) v=Wp[jh*20+4*j+q];
                    else if (j==5 && q==0) v=Bp[jh];
                }
                a.s[j]=f2h(v);
            }
            Ahd=a.v;
        }
#pragma unroll 1
        for (int i=0;i<NITER;i++){
            if (i>=8 && i<SEQ+8){
                const int s=i-8;
                const uint2 fa=fhA[s&1][lane]; const uint fb=fhB[s&1][lane];
                H8 fi; fi.u[0]=fa.x; fi.u[1]=fa.y; fi.u[2]=fb; fi.u[3]=0u;
                const f32x4 ch = __builtin_amdgcn_mfma_f32_16x16x32_f16(Ahd, fi.v, Z, 0,0,0);
                if (q<3){
                    const size_t base = (size_t)q*T3 + ((size_t)s*8192 + (size_t)nt*16 + col)*3;
                    if (q==0){
                        const float mx=fmaxf(ch[0],fmaxf(ch[1],ch[2]));
                        const float e0=__expf(ch[0]-mx), e1=__expf(ch[1]-mx), e2=__expf(ch[2]-mx);
                        const float inv=__builtin_amdgcn_rcpf(e0+e1+e2);
                        out[base+0]=e0*inv; out[base+1]=e1*inv; out[base+2]=e2*inv;
                    } else {
                        out[base+0]=__expf(fminf(fmaxf(ch[0],-25.f),25.f));
                        out[base+1]=__expf(fminf(fmaxf(ch[1],-25.f),25.f));
                        out[base+2]=__expf(fminf(fmaxf(ch[2],-25.f),25.f));
                    }
                }
            }
            pipe_barrier();
        }
    }
}

// ---------------------------------------------------------------- launch
extern "C" void kernel_launch(void* const* d_in, const int* in_sizes, int n_in,
                              void* d_out, int out_size, void* d_ws, size_t ws_size,
                              hipStream_t stream)
{
    (void)in_sizes; (void)n_in; (void)out_size; (void)d_ws; (void)ws_size;
    const float* xlni  = (const float*)d_in[0];
    const float* imean = (const float*)d_in[1];
    const float* istd  = (const float*)d_in[2];
    const float* l1w = (const float*)d_in[3];
    const float* l1b = (const float*)d_in[4];
    const float* g1  = (const float*)d_in[5];
    const float* l2w = (const float*)d_in[6];
    const float* l2b = (const float*)d_in[7];
    const float* g2  = (const float*)d_in[8];
    const float* wih1=(const float*)d_in[9];
    const float* whh1=(const float*)d_in[10];
    const float* bih1=(const float*)d_in[11];
    const float* bhh1=(const float*)d_in[12];
    const float* g3  =(const float*)d_in[13];
    const float* b3n =(const float*)d_in[14];
    const float* wih2=(const float*)d_in[15];
    const float* whh2=(const float*)d_in[16];
    const float* bih2=(const float*)d_in[17];
    const float* bhh2=(const float*)d_in[18];
    const float* g4  =(const float*)d_in[19];
    const float* l3w =(const float*)d_in[20];
    const float* l3b =(const float*)d_in[21];
    const float* g5  =(const float*)d_in[22];
    const float* l4w =(const float*)d_in[23];
    const float* l4b =(const float*)d_in[24];
    const float* g6  =(const float*)d_in[25];
    const float* l5w =(const float*)d_in[26];
    const float* l5b =(const float*)d_in[27];
    const float* wfw =(const float*)d_in[28];
    const float* wfb =(const float*)d_in[29];
    const float* sfw =(const float*)d_in[30];
    const float* sfb =(const float*)d_in[31];
    const float* dfw =(const float*)d_in[32];
    const float* dfb =(const float*)d_in[33];

    k_all<<<NTL, 640, 0, stream>>>(
        xlni, imean, istd,
        l1w, l1b, g1, l2w, l2b, g2,
        wih1, whh1, bih1, bhh1, g3, b3n,
        wih2, whh2, bih2, bhh2,
        g4, l3w, l3b, g5, l4w, l4b, g6, l5w, l5b,
        wfw, wfb, sfw, sfb, dfw, dfb,
        (float*)d_out);
}

// Round 11
// 278.438 us; speedup vs baseline: 1.0743x; 1.0743x over previous
//
#include <hip/hip_runtime.h>
#include <hip/hip_fp16.h>

#define SEQ    128
#define QUADS  32                /* SEQ/4: four timesteps per barrier iteration */
#define NITER  (QUADS+3)
#define NTL    512               /* n-tiles of 16; one block per tile */
#define TOT    (SEQ*8192)        /* 1048576 */
#define T3     (TOT*3)

typedef __attribute__((ext_vector_type(8))) _Float16 half8;
typedef __attribute__((ext_vector_type(4))) float    f32x4;
union H8 { half8 v; ushort s[8]; uint u[4]; };

// cheap silu (measured-best form)
__device__ __forceinline__ float siluf(float x){ return x*__builtin_amdgcn_rcpf(1.f+__expf(-x)); }
__device__ __forceinline__ ushort f2h(float x){ _Float16 h=(_Float16)x; return __builtin_bit_cast(ushort,h); }
__device__ __forceinline__ float  h2fl(ushort u){ _Float16 h=__builtin_bit_cast(_Float16,u); return (float)h; }
__device__ __forceinline__ float  lo16(uint u){ return h2fl((ushort)(u&0xFFFFu)); }
__device__ __forceinline__ float  hi16(uint u){ return h2fl((ushort)(u>>16)); }
__device__ __forceinline__ uint   pkf(float a, float b){ auto r=__builtin_amdgcn_cvt_pkrtz(a,b); return __builtin_bit_cast(uint,r); }

// RAW pipeline barrier: LDS-only ordering (lgkmcnt); vmcnt floats across
// barriers (inputs read-only, outputs never read back). Validated R1.
__device__ __forceinline__ void pipe_barrier(){
    __builtin_amdgcn_sched_barrier(0);
    asm volatile("s_waitcnt lgkmcnt(0)" ::: "memory");
    __builtin_amdgcn_s_barrier();
    __builtin_amdgcn_sched_barrier(0);
}

// K-slot permutation: k-slot 8g+j holds unit 4j+g (j<5); bias at k-slot 5 (g=0,j=5).
__device__ __forceinline__ half8 packB(int q, float v0,float v1,float v2,float v3,float v4,float vb){
    H8 o;
    o.u[0]=pkf(v0,v1);
    o.u[1]=pkf(v2,v3);
    o.u[2]=pkf(v4, (q==0)? vb : 0.f);
    o.u[3]=0u;
    return o.v;
}

// gates pre-scaled by -1/ln2 (-2/ln2 for g row). 5 exp + 3 rcp (R6-validated).
__device__ __forceinline__ float gate_step(const f32x4 a, float& c){
    const float ei=__builtin_amdgcn_exp2f(a[0]);
    const float ef=__builtin_amdgcn_exp2f(a[1]);
    const float eg=__builtin_amdgcn_exp2f(a[2]);
    const float eo=__builtin_amdgcn_exp2f(a[3]);
    const float rf =__builtin_amdgcn_rcpf(1.f+ef);
    const float rig=__builtin_amdgcn_rcpf((1.f+ei)*(1.f+eg));
    c = c*rf + (1.f-eg)*rig;
    const float ec=__builtin_amdgcn_exp2f(fminf(-2.885390082f*c,60.f));
    const float roc=__builtin_amdgcn_rcpf((1.f+eo)*(1.f+ec));
    return (1.f-ec)*roc;
}

// known-good butterfly (R10's permlane variant failed correctness — reverted)
__device__ __forceinline__ void red4(float& s, float& ss){
    s  += __shfl_xor(s,16,64);  s  += __shfl_xor(s,32,64);
    ss += __shfl_xor(ss,16,64); ss += __shfl_xor(ss,32,64);
}

// 20-row GEMV tile row->unit maps
__device__ __forceinline__ int uemap(int tt, int m){
    if (tt==0) return 4*(m&3)+(m>>2);
    return ((m&3)==0) ? 16+(m>>2) : -1;
}

// ---------------------------------------------------------------- single fused kernel
// 512 blocks x 8 waves, one n-tile per block, 4 steps per barrier iteration.
// LDS = 30720 B -> 2 blocks/CU co-resident -> 16 waves/CU (4/SIMD). [R8: 162us]
// Roles: 0=LSTM1 1=LSTM2 2=PRE{s0,s1} 3=PRE{s2,s3} 4..7=POST step (rl-4).
// CO-RESIDENT ROLE ROTATION (the single change vs R8): co-resident blocks are
// b and b+256 (XCD round-robin) -> differ in bit 8. Rotate role map by 2 SIMDs
// on that bit so each SIMD hosts {hot role from one block + cold from the other}:
// per-SIMD issue 4340/4180/2420/2420 -> ~3380/3300/3380/3300 (max -22%).
__global__ __launch_bounds__(512, 4) void k_all(
    const float* __restrict__ xlni, const float* __restrict__ imean, const float* __restrict__ istd,
    const float* __restrict__ w1,  const float* __restrict__ b1,  const float* __restrict__ g1,
    const float* __restrict__ w2,  const float* __restrict__ b2,  const float* __restrict__ g2,
    const float* __restrict__ wih1, const float* __restrict__ whh1,
    const float* __restrict__ bih1, const float* __restrict__ bhh1,
    const float* __restrict__ ln3g, const float* __restrict__ ln3b,
    const float* __restrict__ wih2, const float* __restrict__ whh2,
    const float* __restrict__ bih2, const float* __restrict__ bhh2,
    const float* __restrict__ g4, const float* __restrict__ w3, const float* __restrict__ b3,
    const float* __restrict__ g5, const float* __restrict__ w4, const float* __restrict__ b4,
    const float* __restrict__ g6, const float* __restrict__ w5, const float* __restrict__ b5,
    const float* __restrict__ wfw, const float* __restrict__ wfb,
    const float* __restrict__ sfw, const float* __restrict__ sfb,
    const float* __restrict__ dfw, const float* __restrict__ dfb,
    float* __restrict__ out)
{
    // 3-word fragments (4th word always 0) -> 30720 B total -> 2 blocks/CU
    __shared__ uint2 preFa[2][4][64];
    __shared__ uint  preFb[2][4][64];
    __shared__ uint2 preXa[2][4][64];
    __shared__ uint  preXb[2][4][64];
    __shared__ uint2 x3Fa[2][4][64];
    __shared__ uint  x3Fb[2][4][64];
    __shared__ uint2 x3Xa[2][4][64];
    __shared__ uint  x3Xb[2][4][64];
    __shared__ uint2 x4Xa[2][4][64];
    __shared__ uint  x4Xb[2][4][64];

    const int tid  = threadIdx.x;
    const int wv   = tid >> 6;
    const int lane = tid & 63;
    const int col  = lane & 15, q = lane >> 4;
    const int nt   = blockIdx.x;
    // role rotation by 2 SIMDs keyed on bit 8 (differs between co-resident blocks)
    const int rl   = (((nt>>8)&1)? ((wv&4)|((wv+2)&3)) : wv);
    const f32x4 Z  = {0.f,0.f,0.f,0.f};

    if (rl == 2 || rl == 3){
        // ================= PRE (2 steps/iter: s0, s0+1) =================
        const int s0 = (rl==2)? 0 : 2;
        float wd[5], wu[5], ws0[5], ws1[5], ws2[5], ws3[5];
#pragma unroll
        for (int t=0;t<5;t++){
            const int u = 4*t+q;
            wd[t]=w1[u*6+0]; wu[t]=w1[u*6+1];
            ws0[t]=w1[u*6+2]+b1[u]; ws1[t]=w1[u*6+3]+b1[u];
            ws2[t]=w1[u*6+4]+b1[u]; ws3[t]=w1[u*6+5]+b1[u];
        }
        half8 Aw2[2];
#pragma unroll
        for (int tt=0;tt<2;tt++){
            const int u = uemap(tt, col);
            H8 a;
#pragma unroll
            for (int j=0;j<8;j++){
                float v=0.f;
                if (u>=0){
                    if (j<5){ const int un=4*j+q; v = w2[u*20+un]*g1[un]; }
                    else if (j==5 && q==0) v = b2[u];
                }
                a.s[j]=f2h(v);
            }
            Aw2[tt]=a.v;
        }
        const float mu0=imean[0], mu1=imean[1];
        const float ri0=1.f/istd[0], ri1=1.f/istd[1];

        auto pre_step = [&](float D0, float D1, float RR, int p, int sub){
            const float xd = (__logf(1e-5f+D0)-mu0)*ri0;
            const float xu = (__logf(fminf(fmaxf(D1,100.f),60000.f))-mu1)*ri1;
            int r = (int)fmaxf(RR,1.f)-1; r = r<0?0:(r>3?3:r);

            float av[5], s=0.f, ss=0.f;
#pragma unroll
            for (int t=0;t<5;t++){
                const float wsel = (r==0)?ws0[t]:(r==1)?ws1[t]:(r==2)?ws2[t]:ws3[t];
                const float v = wd[t]*xd + wu[t]*xu + wsel;
                av[t]=siluf(v); s+=av[t]; ss+=av[t]*av[t];
            }
            red4(s,ss);
            float mn=s*0.05f, var=fmaxf(ss*0.05f-mn*mn,0.f);
            float rs=__builtin_amdgcn_rsqf(var+1e-5f); float mr=mn*rs;
            const half8 yf = packB(q, av[0]*rs-mr, av[1]*rs-mr, av[2]*rs-mr, av[3]*rs-mr, av[4]*rs-mr, 1.0f);
            const f32x4 c0 = __builtin_amdgcn_mfma_f32_16x16x32_f16(Aw2[0], yf, Z, 0,0,0);
            const f32x4 c1 = __builtin_amdgcn_mfma_f32_16x16x32_f16(Aw2[1], yf, Z, 0,0,0);
            float X2[5]; s=0.f; ss=0.f;
#pragma unroll
            for (int t=0;t<5;t++){
                const float v = siluf(t<4 ? c0[t] : c1[0]);
                X2[t]=v; s+=v; ss+=v*v;
            }
            red4(s,ss);
            mn=s*0.05f; var=fmaxf(ss*0.05f-mn*mn,0.f);
            rs=__builtin_amdgcn_rsqf(var+1e-5f); mr=mn*rs;
            const half8 xnf = packB(q, X2[0]*rs-mr, X2[1]*rs-mr, X2[2]*rs-mr, X2[3]*rs-mr, X2[4]*rs-mr, 1.0f);

            H8 fo; fo.v = xnf;
            preFa[p][sub][lane] = make_uint2(fo.u[0],fo.u[1]);
            preFb[p][sub][lane] = fo.u[2];
            preXa[p][sub][lane] = make_uint2(pkf(X2[0],X2[1]), pkf(X2[2],X2[3]));
            preXb[p][sub][lane] = pkf(X2[4],0.f);
        };

        float cd0[2], cd1[2], cr[2];
#pragma unroll
        for (int s=0;s<2;s++){
            const size_t ib = ((size_t)(s0+s)*8192 + (size_t)nt*16 + col)*3;
            cd0[s]=xlni[ib]; cd1[s]=xlni[ib+1]; cr[s]=xlni[ib+2];
        }
#pragma unroll 1
        for (int j=0;j<NITER;j++){
            if (j<QUADS){
                float nd0[2], nd1[2], nr[2];
#pragma unroll
                for (int s=0;s<2;s++){
                    int st = 4*(j+1)+s0+s; st = (st<SEQ)? st : SEQ-1;
                    const size_t ib = ((size_t)st*8192 + (size_t)nt*16 + col)*3;
                    nd0[s]=xlni[ib]; nd1[s]=xlni[ib+1]; nr[s]=xlni[ib+2];
                }
                const int p = j&1;
#pragma unroll
                for (int s=0;s<2;s++) pre_step(cd0[s],cd1[s],cr[s], p, s0+s);
#pragma unroll
                for (int s=0;s<2;s++){ cd0[s]=nd0[s]; cd1[s]=nd1[s]; cr[s]=nr[s]; }
            }
            pipe_barrier();
        }
    } else if (rl == 0){
        // ================= LSTM1 (whole; 4 steps/iter) =================
        half8 Aih1[5], Ahh1[5];
#pragma unroll
        for (int t=0;t<5;t++){
            const int M = t*16 + col, u = M>>2, g = M&3, r = g*20+u;
            const float sc = (g==2)? -2.885390082f : -1.442695041f;
            H8 a0,a1;
#pragma unroll
            for (int j=0;j<8;j++){
                float vih1=0.f, vhh1=0.f;
                if (j<5){
                    const int un = 4*j+q;
                    vih1 = wih1[r*20+un]*g2[un]*sc;
                    vhh1 = whh1[r*20+un]*sc;
                } else if (j==5 && q==0){
                    vih1 = (bih1[r]+bhh1[r])*sc;
                }
                a0.s[j]=f2h(vih1); a1.s[j]=f2h(vhh1);
            }
            Aih1[t]=a0.v; Ahh1[t]=a1.v;
        }
        float c1g[5]={0,0,0,0,0};
        half8 h1f; { H8 z; z.u[0]=0;z.u[1]=0;z.u[2]=0;z.u[3]=0; h1f=z.v; }

#pragma unroll 1
        for (int j=0;j<NITER;j++){
            if (j>=1 && j<QUADS+1){
                const int p=(j-1)&1;
                uint2 fa[4]; uint fb[4]; uint2 xa[4]; uint xb[4];
#pragma unroll
                for (int s=0;s<4;s++){
                    fa[s]=preFa[p][s][lane]; fb[s]=preFb[p][s][lane];
                    xa[s]=preXa[p][s][lane]; xb[s]=preXb[p][s][lane];
                }
#pragma unroll
                for (int s=0;s<4;s++){
                    H8 fi; fi.u[0]=fa[s].x; fi.u[1]=fa[s].y; fi.u[2]=fb[s]; fi.u[3]=0u;
                    f32x4 ac[5];
#pragma unroll
                    for (int t=0;t<5;t++){
                        ac[t] = __builtin_amdgcn_mfma_f32_16x16x32_f16(Aih1[t], fi.v, Z, 0,0,0);
                        ac[t] = __builtin_amdgcn_mfma_f32_16x16x32_f16(Ahh1[t], h1f, ac[t], 0,0,0);
                    }
                    const float x2r[5] = { lo16(xa[s].x), hi16(xa[s].x), lo16(xa[s].y), hi16(xa[s].y), lo16(xb[s]) };
                    float x3v[5], h1v[5], sm=0.f, ssm=0.f;
#pragma unroll
                    for (int t=0;t<5;t++){
                        const float h = gate_step(ac[t], c1g[t]);
                        h1v[t]=h;
                        const float xv = x2r[t]+h;
                        x3v[t]=xv; sm+=xv; ssm+=xv*xv;
                    }
                    h1f = packB(q, h1v[0],h1v[1],h1v[2],h1v[3],h1v[4], 0.f);
                    red4(sm,ssm);
                    const float mn=sm*0.05f; float var=fmaxf(ssm*0.05f-mn*mn,0.f);
                    const float rs=__builtin_amdgcn_rsqf(var+1e-5f), mr=mn*rs;
                    const half8 x3f = packB(q, x3v[0]*rs-mr, x3v[1]*rs-mr, x3v[2]*rs-mr, x3v[3]*rs-mr, x3v[4]*rs-mr, 1.0f);
                    H8 fo; fo.v = x3f;
                    x3Fa[p][s][lane] = make_uint2(fo.u[0],fo.u[1]);
                    x3Fb[p][s][lane] = fo.u[2];
                    x3Xa[p][s][lane] = make_uint2(pkf(x3v[0],x3v[1]), pkf(x3v[2],x3v[3]));
                    x3Xb[p][s][lane] = pkf(x3v[4],0.f);
                }
            }
            pipe_barrier();
        }
    } else if (rl == 1){
        // ================= LSTM2 (whole; 4 steps/iter) =================
        half8 Aa2[5], Ahh2[5];
#pragma unroll
        for (int t=0;t<5;t++){
            const int M = t*16 + col, u = M>>2, g = M&3, r = g*20+u;
            const float sc = (g==2)? -2.885390082f : -1.442695041f;
            H8 a0,a1;
#pragma unroll
            for (int j=0;j<8;j++){
                float va2=0.f, vhh2=0.f;
                if (j<5){
                    const int un = 4*j+q;
                    va2  = wih2[r*20+un]*ln3g[un]*sc;
                    vhh2 = whh2[r*20+un]*sc;
                } else if (j==5 && q==0){
                    float b2 = bih2[r]+bhh2[r];
                    for (int kk=0;kk<20;kk++) b2 += wih2[r*20+kk]*ln3b[kk];
                    va2 = b2*sc;
                }
                a0.s[j]=f2h(va2); a1.s[j]=f2h(vhh2);
            }
            Aa2[t]=a0.v; Ahh2[t]=a1.v;
        }
        float c2g[5]={0,0,0,0,0};
        half8 h2f; { H8 z; z.u[0]=0;z.u[1]=0;z.u[2]=0;z.u[3]=0; h2f=z.v; }

#pragma unroll 1
        for (int j=0;j<NITER;j++){
            if (j>=2 && j<QUADS+2){
                const int p=(j-2)&1;
                uint2 fa[4]; uint fb[4]; uint2 xa[4]; uint xb[4];
#pragma unroll
                for (int s=0;s<4;s++){
                    fa[s]=x3Fa[p][s][lane]; fb[s]=x3Fb[p][s][lane];
                    xa[s]=x3Xa[p][s][lane]; xb[s]=x3Xb[p][s][lane];
                }
#pragma unroll
                for (int s=0;s<4;s++){
                    H8 fi; fi.u[0]=fa[s].x; fi.u[1]=fa[s].y; fi.u[2]=fb[s]; fi.u[3]=0u;
                    f32x4 ac[5];
#pragma unroll
                    for (int t=0;t<5;t++){
                        ac[t] = __builtin_amdgcn_mfma_f32_16x16x32_f16(Aa2[t],  fi.v, Z, 0,0,0);
                        ac[t] = __builtin_amdgcn_mfma_f32_16x16x32_f16(Ahh2[t], h2f, ac[t], 0,0,0);
                    }
                    const float x3v[5] = { lo16(xa[s].x), hi16(xa[s].x), lo16(xa[s].y), hi16(xa[s].y), lo16(xb[s]) };
                    float h2v[5], x4[5];
#pragma unroll
                    for (int t=0;t<5;t++){
                        h2v[t] = gate_step(ac[t], c2g[t]);
                        x4[t]  = x3v[t] + h2v[t];
                    }
                    h2f = packB(q, h2v[0],h2v[1],h2v[2],h2v[3],h2v[4], 0.f);
                    x4Xa[p][s][lane] = make_uint2(pkf(x4[0],x4[1]), pkf(x4[2],x4[3]));
                    x4Xb[p][s][lane] = pkf(x4[4],0.f);
                }
            }
            pipe_barrier();
        }
    } else {
        // ================= POST + heads (1 step/iter: s = rl-4) =================
        const int sp = rl - 4;
        half8 A3[2], A4[2], A5[2];
#pragma unroll
        for (int tt=0;tt<2;tt++){
            const int u = uemap(tt, col);
            H8 a3,a4,a5;
#pragma unroll
            for (int j=0;j<8;j++){
                float v3=0.f,v4=0.f,v5=0.f;
                if (u>=0){
                    if (j<5){
                        const int un=4*j+q;
                        v3=w3[u*20+un]*g4[un]; v4=w4[u*20+un]*g5[un]; v5=w5[u*20+un]*g6[un];
                    } else if (j==5 && q==0){ v3=b3[u]; v4=b4[u]; v5=b5[u]; }
                }
                a3.s[j]=f2h(v3); a4.s[j]=f2h(v4); a5.s[j]=f2h(v5);
            }
            A3[tt]=a3.v; A4[tt]=a4.v; A5[tt]=a5.v;
        }
        half8 Ahd;
        {
            const int m=col, hd=m>>2, jh=m&3;
            const float* Wp = (hd==0)? wfw : (hd==1)? sfw : dfw;
            const float* Bp = (hd==0)? wfb : (hd==1)? sfb : dfb;
            const bool ok = (hd<3)&&(jh<3);
            H8 a;
#pragma unroll
            for (int j=0;j<8;j++){
                float v=0.f;
                if (ok){
                    if (j<5) v=Wp[jh*20+4*j+q];
                    else if (j==5 && q==0) v=Bp[jh];
                }
                a.s[j]=f2h(v);
            }
            Ahd=a.v;
        }

        auto post_step = [&](uint2 pa, uint pb, int st){
            float x4[5] = { lo16(pa.x), hi16(pa.x), lo16(pa.y), hi16(pa.y), lo16(pb) };

            float s=0.f, ss=0.f;
#pragma unroll
            for (int t=0;t<5;t++){ s+=x4[t]; ss+=x4[t]*x4[t]; }
            red4(s,ss);
            float mn=s*0.05f, var=fmaxf(ss*0.05f-mn*mn,0.f);
            float rs=__builtin_amdgcn_rsqf(var+1e-5f), mr=mn*rs;
            half8 f4 = packB(q, x4[0]*rs-mr, x4[1]*rs-mr, x4[2]*rs-mr, x4[3]*rs-mr, x4[4]*rs-mr, 1.0f);
            f32x4 c0 = __builtin_amdgcn_mfma_f32_16x16x32_f16(A3[0], f4, Z, 0,0,0);
            f32x4 c1 = __builtin_amdgcn_mfma_f32_16x16x32_f16(A3[1], f4, Z, 0,0,0);
            float hh[5]; s=0.f; ss=0.f;
#pragma unroll
            for (int t=0;t<5;t++){ hh[t]=siluf(t<4?c0[t]:c1[0]); s+=hh[t]; ss+=hh[t]*hh[t]; }
            red4(s,ss);
            mn=s*0.05f; var=fmaxf(ss*0.05f-mn*mn,0.f);
            rs=__builtin_amdgcn_rsqf(var+1e-5f); mr=mn*rs;
            half8 f5 = packB(q, hh[0]*rs-mr, hh[1]*rs-mr, hh[2]*rs-mr, hh[3]*rs-mr, hh[4]*rs-mr, 1.0f);
            c0 = __builtin_amdgcn_mfma_f32_16x16x32_f16(A4[0], f5, Z, 0,0,0);
            c1 = __builtin_amdgcn_mfma_f32_16x16x32_f16(A4[1], f5, Z, 0,0,0);
            float xp[5]; s=0.f; ss=0.f;
#pragma unroll
            for (int t=0;t<5;t++){ xp[t]=x4[t]+siluf(t<4?c0[t]:c1[0]); s+=xp[t]; ss+=xp[t]*xp[t]; }
            red4(s,ss);
            mn=s*0.05f; var=fmaxf(ss*0.05f-mn*mn,0.f);
            rs=__builtin_amdgcn_rsqf(var+1e-5f); mr=mn*rs;
            half8 f6 = packB(q, xp[0]*rs-mr, xp[1]*rs-mr, xp[2]*rs-mr, xp[3]*rs-mr, xp[4]*rs-mr, 1.0f);
            c0 = __builtin_amdgcn_mfma_f32_16x16x32_f16(A5[0], f6, Z, 0,0,0);
            c1 = __builtin_amdgcn_mfma_f32_16x16x32_f16(A5[1], f6, Z, 0,0,0);
            float xfv[5];
#pragma unroll
            for (int t=0;t<5;t++) xfv[t]=siluf(t<4?c0[t]:c1[0]);
            half8 fh = packB(q, xfv[0],xfv[1],xfv[2],xfv[3],xfv[4], 1.0f);
            const f32x4 ch = __builtin_amdgcn_mfma_f32_16x16x32_f16(Ahd, fh, Z, 0,0,0);

            if (q<3){
                const size_t base = (size_t)q*T3 + ((size_t)st*8192 + (size_t)nt*16 + col)*3;
                if (q==0){
                    const float mx=fmaxf(ch[0],fmaxf(ch[1],ch[2]));
                    const float e0=__expf(ch[0]-mx), e1=__expf(ch[1]-mx), e2=__expf(ch[2]-mx);
                    const float inv=__builtin_amdgcn_rcpf(e0+e1+e2);
                    out[base+0]=e0*inv; out[base+1]=e1*inv; out[base+2]=e2*inv;
                } else {
                    out[base+0]=__expf(fminf(fmaxf(ch[0],-25.f),25.f));
                    out[base+1]=__expf(fminf(fmaxf(ch[1],-25.f),25.f));
                    out[base+2]=__expf(fminf(fmaxf(ch[2],-25.f),25.f));
                }
            }
        };

#pragma unroll 1
        for (int j=0;j<NITER;j++){
            if (j>=3){
                const int pr = j-3;          // quad index
                const int p  = pr&1;
                const uint2 pa = x4Xa[p][sp][lane];
                const uint  pb = x4Xb[p][sp][lane];
                post_step(pa, pb, 4*pr+sp);
            }
            pipe_barrier();
        }
    }
}

// ---------------------------------------------------------------- launch
extern "C" void kernel_launch(void* const* d_in, const int* in_sizes, int n_in,
                              void* d_out, int out_size, void* d_ws, size_t ws_size,
                              hipStream_t stream)
{
    (void)in_sizes; (void)n_in; (void)out_size; (void)d_ws; (void)ws_size;
    const float* xlni  = (const float*)d_in[0];
    const float* imean = (const float*)d_in[1];
    const float* istd  = (const float*)d_in[2];
    const float* l1w = (const float*)d_in[3];
    const float* l1b = (const float*)d_in[4];
    const float* g1  = (const float*)d_in[5];
    const float* l2w = (const float*)d_in[6];
    const float* l2b = (const float*)d_in[7];
    const float* g2  = (const float*)d_in[8];
    const float* wih1=(const float*)d_in[9];
    const float* whh1=(const float*)d_in[10];
    const float* bih1=(const float*)d_in[11];
    const float* bhh1=(const float*)d_in[12];
    const float* g3  =(const float*)d_in[13];
    const float* b3n =(const float*)d_in[14];
    const float* wih2=(const float*)d_in[15];
    const float* whh2=(const float*)d_in[16];
    const float* bih2=(const float*)d_in[17];
    const float* bhh2=(const float*)d_in[18];
    const float* g4  =(const float*)d_in[19];
    const float* l3w =(const float*)d_in[20];
    const float* l3b =(const float*)d_in[21];
    const float* g5  =(const float*)d_in[22];
    const float* l4w =(const float*)d_in[23];
    const float* l4b =(const float*)d_in[24];
    const float* g6  =(const float*)d_in[25];
    const float* l5w =(const float*)d_in[26];
    const float* l5b =(const float*)d_in[27];
    const float* wfw =(const float*)d_in[28];
    const float* wfb =(const float*)d_in[29];
    const float* sfw =(const float*)d_in[30];
    const float* sfb =(const float*)d_in[31];
    const float* dfw =(const float*)d_in[32];
    const float* dfb =(const float*)d_in[33];

    k_all<<<NTL, 512, 0, stream>>>(
        xlni, imean, istd,
        l1w, l1b, g1, l2w, l2b, g2,
        wih1, whh1, bih1, bhh1, g3, b3n,
        wih2, whh2, bih2, bhh2,
        g4, l3w, l3b, g5, l4w, l4b, g6, l5w, l5b,
        wfw, wfb, sfw, sfb, dfw, dfb,
        (float*)d_out);
}

// Round 13
// 268.714 us; speedup vs baseline: 1.1131x; 1.0362x over previous
//
#include <hip/hip_runtime.h>
#include <hip/hip_fp16.h>

#define SEQ    128
#define QUADS  32                /* SEQ/4: four timesteps per barrier iteration */
#define NITER  (QUADS+3)
#define NTL    512               /* n-tiles of 16; one block per tile */
#define TOT    (SEQ*8192)        /* 1048576 */
#define T3     (TOT*3)

typedef __attribute__((ext_vector_type(8))) _Float16 half8;
typedef __attribute__((ext_vector_type(4))) float    f32x4;
union H8 { half8 v; ushort s[8]; uint u[4]; };

// cheap silu (measured-best form)
__device__ __forceinline__ float siluf(float x){ return x*__builtin_amdgcn_rcpf(1.f+__expf(-x)); }
__device__ __forceinline__ ushort f2h(float x){ _Float16 h=(_Float16)x; return __builtin_bit_cast(ushort,h); }
__device__ __forceinline__ uint   pkf(float a, float b){ auto r=__builtin_amdgcn_cvt_pkrtz(a,b); return __builtin_bit_cast(uint,r); }

// RAW pipeline barrier: LDS-only ordering (lgkmcnt); vmcnt floats across
// barriers (inputs read-only, outputs never read back). Validated R1.
__device__ __forceinline__ void pipe_barrier(){
    __builtin_amdgcn_sched_barrier(0);
    asm volatile("s_waitcnt lgkmcnt(0)" ::: "memory");
    __builtin_amdgcn_s_barrier();
    __builtin_amdgcn_sched_barrier(0);
}

// K-slot permutation: k-slot 8g+j holds unit 4j+g (j<5); bias at k-slot 5 (g=0,j=5).
__device__ __forceinline__ half8 packB(int q, float v0,float v1,float v2,float v3,float v4,float vb){
    H8 o;
    o.u[0]=pkf(v0,v1);
    o.u[1]=pkf(v2,v3);
    o.u[2]=pkf(v4, (q==0)? vb : 0.f);
    o.u[3]=0u;
    return o.v;
}

// gates pre-scaled by -1/ln2 (-2/ln2 for g row). 5 exp + 3 rcp (R6-validated).
__device__ __forceinline__ float gate_step(const f32x4 a, float& c){
    const float ei=__builtin_amdgcn_exp2f(a[0]);
    const float ef=__builtin_amdgcn_exp2f(a[1]);
    const float eg=__builtin_amdgcn_exp2f(a[2]);
    const float eo=__builtin_amdgcn_exp2f(a[3]);
    const float rf =__builtin_amdgcn_rcpf(1.f+ef);
    const float rig=__builtin_amdgcn_rcpf((1.f+ei)*(1.f+eg));
    c = c*rf + (1.f-eg)*rig;
    const float ec=__builtin_amdgcn_exp2f(fminf(-2.885390082f*c,60.f));
    const float roc=__builtin_amdgcn_rcpf((1.f+eo)*(1.f+ec));
    return (1.f-ec)*roc;
}

// known-good butterfly
__device__ __forceinline__ void red4(float& s, float& ss){
    s  += __shfl_xor(s,16,64);  s  += __shfl_xor(s,32,64);
    ss += __shfl_xor(ss,16,64); ss += __shfl_xor(ss,32,64);
}

// 20-row GEMV tile row->unit maps
__device__ __forceinline__ int uemap(int tt, int m){
    if (tt==0) return 4*(m&3)+(m>>2);
    return ((m&3)==0) ? 16+(m>>2) : -1;
}

// ---------------------------------------------------------------- single fused kernel
// 512 blocks x 8 waves, one n-tile per block, 4 steps per barrier iteration.
// R8 skeleton (162us) + R11 rotation (neutral, kept) + R12 change:
// RAW residual paths (preX/x3X/x4X) stored as f32 in LDS — deletes the
// ~40 cvt_f32_f16+shift unpacks and ~10 cvt_pkrtz packs per step that served
// only to halve LDS footprint (no longer needed: 43KB/block still gives
// 2 blocks/CU -> 16 waves/CU -> 4 waves/SIMD, the proven-optimal occupancy).
// Fragment paths stay f16 (MFMA operands). PRE norm constants folded.
__global__ __launch_bounds__(512, 4) void k_all(
    const float* __restrict__ xlni, const float* __restrict__ imean, const float* __restrict__ istd,
    const float* __restrict__ w1,  const float* __restrict__ b1,  const float* __restrict__ g1,
    const float* __restrict__ w2,  const float* __restrict__ b2,  const float* __restrict__ g2,
    const float* __restrict__ wih1, const float* __restrict__ whh1,
    const float* __restrict__ bih1, const float* __restrict__ bhh1,
    const float* __restrict__ ln3g, const float* __restrict__ ln3b,
    const float* __restrict__ wih2, const float* __restrict__ whh2,
    const float* __restrict__ bih2, const float* __restrict__ bhh2,
    const float* __restrict__ g4, const float* __restrict__ w3, const float* __restrict__ b3,
    const float* __restrict__ g5, const float* __restrict__ w4, const float* __restrict__ b4,
    const float* __restrict__ g6, const float* __restrict__ w5, const float* __restrict__ b5,
    const float* __restrict__ wfw, const float* __restrict__ wfb,
    const float* __restrict__ sfw, const float* __restrict__ sfb,
    const float* __restrict__ dfw, const float* __restrict__ dfb,
    float* __restrict__ out)
{
    // fragments (f16, MFMA operands): 3-word form
    __shared__ uint2  preFa[2][4][64];
    __shared__ uint   preFb[2][4][64];
    __shared__ uint2  x3Fa[2][4][64];
    __shared__ uint   x3Fb[2][4][64];
    // raw residual values: f32 (no pack/unpack)
    __shared__ float4 preXv[2][4][64];
    __shared__ float  preXw[2][4][64];
    __shared__ float4 x3Xv[2][4][64];
    __shared__ float  x3Xw[2][4][64];
    __shared__ float4 x4Xv[2][4][64];
    __shared__ float  x4Xw[2][4][64];
    // total = 43,008 B -> 2+ blocks/CU co-resident (4 waves/SIMD preserved)

    const int tid  = threadIdx.x;
    const int wv   = tid >> 6;
    const int lane = tid & 63;
    const int col  = lane & 15, q = lane >> 4;
    const int nt   = blockIdx.x;
    // role rotation by 2 SIMDs keyed on bit 8 (neutral R11; kept)
    const int rl   = (((nt>>8)&1)? ((wv&4)|((wv+2)&3)) : wv);
    const f32x4 Z  = {0.f,0.f,0.f,0.f};

    if (rl == 2 || rl == 3){
        // ================= PRE (2 steps/iter: s0, s0+1) =================
        const int s0 = (rl==2)? 0 : 2;
        // normalization folded into weights: v = wdn*log(D0') + wun*log(D1') + wsel'
        const float ri0=1.f/istd[0], ri1=1.f/istd[1];
        const float mu0=imean[0], mu1=imean[1];
        float wdn[5], wun[5], ws0[5], ws1[5], ws2[5], ws3[5];
#pragma unroll
        for (int t=0;t<5;t++){
            const int u = 4*t+q;
            wdn[t]=w1[u*6+0]*ri0; wun[t]=w1[u*6+1]*ri1;
            const float off = b1[u] - wdn[t]*mu0 - wun[t]*mu1;
            ws0[t]=w1[u*6+2]+off; ws1[t]=w1[u*6+3]+off;
            ws2[t]=w1[u*6+4]+off; ws3[t]=w1[u*6+5]+off;
        }
        half8 Aw2[2];
#pragma unroll
        for (int tt=0;tt<2;tt++){
            const int u = uemap(tt, col);
            H8 a;
#pragma unroll
            for (int j=0;j<8;j++){
                float v=0.f;
                if (u>=0){
                    if (j<5){ const int un=4*j+q; v = w2[u*20+un]*g1[un]; }
                    else if (j==5 && q==0) v = b2[u];
                }
                a.s[j]=f2h(v);
            }
            Aw2[tt]=a.v;
        }

        auto pre_step = [&](float D0, float D1, float RR, int p, int sub){
            const float xd = __logf(1e-5f+D0);
            const float xu = __logf(fminf(fmaxf(D1,100.f),60000.f));
            int r = (int)fmaxf(RR,1.f)-1; r = r<0?0:(r>3?3:r);

            float av[5], s=0.f, ss=0.f;
#pragma unroll
            for (int t=0;t<5;t++){
                const float wsel = (r==0)?ws0[t]:(r==1)?ws1[t]:(r==2)?ws2[t]:ws3[t];
                const float v = wdn[t]*xd + wun[t]*xu + wsel;
                av[t]=siluf(v); s+=av[t]; ss+=av[t]*av[t];
            }
            red4(s,ss);
            float mn=s*0.05f, var=fmaxf(ss*0.05f-mn*mn,0.f);
            float rs=__builtin_amdgcn_rsqf(var+1e-5f); float mr=mn*rs;
            const half8 yf = packB(q, av[0]*rs-mr, av[1]*rs-mr, av[2]*rs-mr, av[3]*rs-mr, av[4]*rs-mr, 1.0f);
            const f32x4 c0 = __builtin_amdgcn_mfma_f32_16x16x32_f16(Aw2[0], yf, Z, 0,0,0);
            const f32x4 c1 = __builtin_amdgcn_mfma_f32_16x16x32_f16(Aw2[1], yf, Z, 0,0,0);
            float X2[5]; s=0.f; ss=0.f;
#pragma unroll
            for (int t=0;t<5;t++){
                const float v = siluf(t<4 ? c0[t] : c1[0]);
                X2[t]=v; s+=v; ss+=v*v;
            }
            red4(s,ss);
            mn=s*0.05f; var=fmaxf(ss*0.05f-mn*mn,0.f);
            rs=__builtin_amdgcn_rsqf(var+1e-5f); mr=mn*rs;
            const half8 xnf = packB(q, X2[0]*rs-mr, X2[1]*rs-mr, X2[2]*rs-mr, X2[3]*rs-mr, X2[4]*rs-mr, 1.0f);

            H8 fo; fo.v = xnf;
            preFa[p][sub][lane] = make_uint2(fo.u[0],fo.u[1]);
            preFb[p][sub][lane] = fo.u[2];
            preXv[p][sub][lane] = make_float4(X2[0],X2[1],X2[2],X2[3]);
            preXw[p][sub][lane] = X2[4];
        };

        float cd0[2], cd1[2], cr[2];
#pragma unroll
        for (int s=0;s<2;s++){
            const size_t ib = ((size_t)(s0+s)*8192 + (size_t)nt*16 + col)*3;
            cd0[s]=xlni[ib]; cd1[s]=xlni[ib+1]; cr[s]=xlni[ib+2];
        }
#pragma unroll 1
        for (int j=0;j<NITER;j++){
            if (j<QUADS){
                float nd0[2], nd1[2], nr[2];
#pragma unroll
                for (int s=0;s<2;s++){
                    int st = 4*(j+1)+s0+s; st = (st<SEQ)? st : SEQ-1;
                    const size_t ib = ((size_t)st*8192 + (size_t)nt*16 + col)*3;
                    nd0[s]=xlni[ib]; nd1[s]=xlni[ib+1]; nr[s]=xlni[ib+2];
                }
                const int p = j&1;
#pragma unroll
                for (int s=0;s<2;s++) pre_step(cd0[s],cd1[s],cr[s], p, s0+s);
#pragma unroll
                for (int s=0;s<2;s++){ cd0[s]=nd0[s]; cd1[s]=nd1[s]; cr[s]=nr[s]; }
            }
            pipe_barrier();
        }
    } else if (rl == 0){
        // ================= LSTM1 (whole; 4 steps/iter) =================
        half8 Aih1[5], Ahh1[5];
#pragma unroll
        for (int t=0;t<5;t++){
            const int M = t*16 + col, u = M>>2, g = M&3, r = g*20+u;
            const float sc = (g==2)? -2.885390082f : -1.442695041f;
            H8 a0,a1;
#pragma unroll
            for (int j=0;j<8;j++){
                float vih1=0.f, vhh1=0.f;
                if (j<5){
                    const int un = 4*j+q;
                    vih1 = wih1[r*20+un]*g2[un]*sc;
                    vhh1 = whh1[r*20+un]*sc;
                } else if (j==5 && q==0){
                    vih1 = (bih1[r]+bhh1[r])*sc;
                }
                a0.s[j]=f2h(vih1); a1.s[j]=f2h(vhh1);
            }
            Aih1[t]=a0.v; Ahh1[t]=a1.v;
        }
        float c1g[5]={0,0,0,0,0};
        half8 h1f; { H8 z; z.u[0]=0;z.u[1]=0;z.u[2]=0;z.u[3]=0; h1f=z.v; }

#pragma unroll 1
        for (int j=0;j<NITER;j++){
            if (j>=1 && j<QUADS+1){
                const int p=(j-1)&1;
                uint2 fa[4]; uint fb[4]; float4 xv[4]; float xw[4];
#pragma unroll
                for (int s=0;s<4;s++){
                    fa[s]=preFa[p][s][lane]; fb[s]=preFb[p][s][lane];
                    xv[s]=preXv[p][s][lane]; xw[s]=preXw[p][s][lane];
                }
#pragma unroll
                for (int s=0;s<4;s++){
                    H8 fi; fi.u[0]=fa[s].x; fi.u[1]=fa[s].y; fi.u[2]=fb[s]; fi.u[3]=0u;
                    f32x4 ac[5];
#pragma unroll
                    for (int t=0;t<5;t++){
                        ac[t] = __builtin_amdgcn_mfma_f32_16x16x32_f16(Aih1[t], fi.v, Z, 0,0,0);
                        ac[t] = __builtin_amdgcn_mfma_f32_16x16x32_f16(Ahh1[t], h1f, ac[t], 0,0,0);
                    }
                    const float x2r[5] = { xv[s].x, xv[s].y, xv[s].z, xv[s].w, xw[s] };
                    float x3v[5], h1v[5], sm=0.f, ssm=0.f;
#pragma unroll
                    for (int t=0;t<5;t++){
                        const float h = gate_step(ac[t], c1g[t]);
                        h1v[t]=h;
                        const float xvv = x2r[t]+h;
                        x3v[t]=xvv; sm+=xvv; ssm+=xvv*xvv;
                    }
                    h1f = packB(q, h1v[0],h1v[1],h1v[2],h1v[3],h1v[4], 0.f);
                    red4(sm,ssm);
                    const float mn=sm*0.05f; float var=fmaxf(ssm*0.05f-mn*mn,0.f);
                    const float rs=__builtin_amdgcn_rsqf(var+1e-5f), mr=mn*rs;
                    const half8 x3f = packB(q, x3v[0]*rs-mr, x3v[1]*rs-mr, x3v[2]*rs-mr, x3v[3]*rs-mr, x3v[4]*rs-mr, 1.0f);
                    H8 fo; fo.v = x3f;
                    x3Fa[p][s][lane] = make_uint2(fo.u[0],fo.u[1]);
                    x3Fb[p][s][lane] = fo.u[2];
                    x3Xv[p][s][lane] = make_float4(x3v[0],x3v[1],x3v[2],x3v[3]);
                    x3Xw[p][s][lane] = x3v[4];
                }
            }
            pipe_barrier();
        }
    } else if (rl == 1){
        // ================= LSTM2 (whole; 4 steps/iter) =================
        half8 Aa2[5], Ahh2[5];
#pragma unroll
        for (int t=0;t<5;t++){
            const int M = t*16 + col, u = M>>2, g = M&3, r = g*20+u;
            const float sc = (g==2)? -2.885390082f : -1.442695041f;
            H8 a0,a1;
#pragma unroll
            for (int j=0;j<8;j++){
                float va2=0.f, vhh2=0.f;
                if (j<5){
                    const int un = 4*j+q;
                    va2  = wih2[r*20+un]*ln3g[un]*sc;
                    vhh2 = whh2[r*20+un]*sc;
                } else if (j==5 && q==0){
                    float b2 = bih2[r]+bhh2[r];
                    for (int kk=0;kk<20;kk++) b2 += wih2[r*20+kk]*ln3b[kk];
                    va2 = b2*sc;
                }
                a0.s[j]=f2h(va2); a1.s[j]=f2h(vhh2);
            }
            Aa2[t]=a0.v; Ahh2[t]=a1.v;
        }
        float c2g[5]={0,0,0,0,0};
        half8 h2f; { H8 z; z.u[0]=0;z.u[1]=0;z.u[2]=0;z.u[3]=0; h2f=z.v; }

#pragma unroll 1
        for (int j=0;j<NITER;j++){
            if (j>=2 && j<QUADS+2){
                const int p=(j-2)&1;
                uint2 fa[4]; uint fb[4]; float4 xv[4]; float xw[4];
#pragma unroll
                for (int s=0;s<4;s++){
                    fa[s]=x3Fa[p][s][lane]; fb[s]=x3Fb[p][s][lane];
                    xv[s]=x3Xv[p][s][lane]; xw[s]=x3Xw[p][s][lane];
                }
#pragma unroll
                for (int s=0;s<4;s++){
                    H8 fi; fi.u[0]=fa[s].x; fi.u[1]=fa[s].y; fi.u[2]=fb[s]; fi.u[3]=0u;
                    f32x4 ac[5];
#pragma unroll
                    for (int t=0;t<5;t++){
                        ac[t] = __builtin_amdgcn_mfma_f32_16x16x32_f16(Aa2[t],  fi.v, Z, 0,0,0);
                        ac[t] = __builtin_amdgcn_mfma_f32_16x16x32_f16(Ahh2[t], h2f, ac[t], 0,0,0);
                    }
                    const float x3r[5] = { xv[s].x, xv[s].y, xv[s].z, xv[s].w, xw[s] };
                    float h2v[5], x4[5];
#pragma unroll
                    for (int t=0;t<5;t++){
                        h2v[t] = gate_step(ac[t], c2g[t]);
                        x4[t]  = x3r[t] + h2v[t];
                    }
                    h2f = packB(q, h2v[0],h2v[1],h2v[2],h2v[3],h2v[4], 0.f);
                    x4Xv[p][s][lane] = make_float4(x4[0],x4[1],x4[2],x4[3]);
                    x4Xw[p][s][lane] = x4[4];
                }
            }
            pipe_barrier();
        }
    } else {
        // ================= POST + heads (1 step/iter: s = rl-4) =================
        const int sp = rl - 4;
        half8 A3[2], A4[2], A5[2];
#pragma unroll
        for (int tt=0;tt<2;tt++){
            const int u = uemap(tt, col);
            H8 a3,a4,a5;
#pragma unroll
            for (int j=0;j<8;j++){
                float v3=0.f,v4=0.f,v5=0.f;
                if (u>=0){
                    if (j<5){
                        const int un=4*j+q;
                        v3=w3[u*20+un]*g4[un]; v4=w4[u*20+un]*g5[un]; v5=w5[u*20+un]*g6[un];
                    } else if (j==5 && q==0){ v3=b3[u]; v4=b4[u]; v5=b5[u]; }
                }
                a3.s[j]=f2h(v3); a4.s[j]=f2h(v4); a5.s[j]=f2h(v5);
            }
            A3[tt]=a3.v; A4[tt]=a4.v; A5[tt]=a5.v;
        }
        half8 Ahd;
        {
            const int m=col, hd=m>>2, jh=m&3;
            const float* Wp = (hd==0)? wfw : (hd==1)? sfw : dfw;
            const float* Bp = (hd==0)? wfb : (hd==1)? sfb : dfb;
            const bool ok = (hd<3)&&(jh<3);
            H8 a;
#pragma unroll
            for (int j=0;j<8;j++){
                float v=0.f;
                if (ok){
                    if (j<5) v=Wp[jh*20+4*j+q];
                    else if (j==5 && q==0) v=Bp[jh];
                }
                a.s[j]=f2h(v);
            }
            Ahd=a.v;
        }

        auto post_step = [&](const float4 pv, const float pw, int st){
            float x4[5] = { pv.x, pv.y, pv.z, pv.w, pw };

            float s=0.f, ss=0.f;
#pragma unroll
            for (int t=0;t<5;t++){ s+=x4[t]; ss+=x4[t]*x4[t]; }
            red4(s,ss);
            float mn=s*0.05f, var=fmaxf(ss*0.05f-mn*mn,0.f);
            float rs=__builtin_amdgcn_rsqf(var+1e-5f), mr=mn*rs;
            half8 f4 = packB(q, x4[0]*rs-mr, x4[1]*rs-mr, x4[2]*rs-mr, x4[3]*rs-mr, x4[4]*rs-mr, 1.0f);
            f32x4 c0 = __builtin_amdgcn_mfma_f32_16x16x32_f16(A3[0], f4, Z, 0,0,0);
            f32x4 c1 = __builtin_amdgcn_mfma_f32_16x16x32_f16(A3[1], f4, Z, 0,0,0);
            float hh[5]; s=0.f; ss=0.f;
#pragma unroll
            for (int t=0;t<5;t++){ hh[t]=siluf(t<4?c0[t]:c1[0]); s+=hh[t]; ss+=hh[t]*hh[t]; }
            red4(s,ss);
            mn=s*0.05f; var=fmaxf(ss*0.05f-mn*mn,0.f);
            rs=__builtin_amdgcn_rsqf(var+1e-5f); mr=mn*rs;
            half8 f5 = packB(q, hh[0]*rs-mr, hh[1]*rs-mr, hh[2]*rs-mr, hh[3]*rs-mr, hh[4]*rs-mr, 1.0f);
            c0 = __builtin_amdgcn_mfma_f32_16x16x32_f16(A4[0], f5, Z, 0,0,0);
            c1 = __builtin_amdgcn_mfma_f32_16x16x32_f16(A4[1], f5, Z, 0,0,0);
            float xp[5]; s=0.f; ss=0.f;
#pragma unroll
            for (int t=0;t<5;t++){ xp[t]=x4[t]+siluf(t<4?c0[t]:c1[0]); s+=xp[t]; ss+=xp[t]*xp[t]; }
            red4(s,ss);
            mn=s*0.05f; var=fmaxf(ss*0.05f-mn*mn,0.f);
            rs=__builtin_amdgcn_rsqf(var+1e-5f); mr=mn*rs;
            half8 f6 = packB(q, xp[0]*rs-mr, xp[1]*rs-mr, xp[2]*rs-mr, xp[3]*rs-mr, xp[4]*rs-mr, 1.0f);
            c0 = __builtin_amdgcn_mfma_f32_16x16x32_f16(A5[0], f6, Z, 0,0,0);
            c1 = __builtin_amdgcn_mfma_f32_16x16x32_f16(A5[1], f6, Z, 0,0,0);
            float xfv[5];
#pragma unroll
            for (int t=0;t<5;t++) xfv[t]=siluf(t<4?c0[t]:c1[0]);
            half8 fh = packB(q, xfv[0],xfv[1],xfv[2],xfv[3],xfv[4], 1.0f);
            const f32x4 ch = __builtin_amdgcn_mfma_f32_16x16x32_f16(Ahd, fh, Z, 0,0,0);

            if (q<3){
                const size_t base = (size_t)q*T3 + ((size_t)st*8192 + (size_t)nt*16 + col)*3;
                if (q==0){
                    const float mx=fmaxf(ch[0],fmaxf(ch[1],ch[2]));
                    const float e0=__expf(ch[0]-mx), e1=__expf(ch[1]-mx), e2=__expf(ch[2]-mx);
                    const float inv=__builtin_amdgcn_rcpf(e0+e1+e2);
                    out[base+0]=e0*inv; out[base+1]=e1*inv; out[base+2]=e2*inv;
                } else {
                    out[base+0]=__expf(fminf(fmaxf(ch[0],-25.f),25.f));
                    out[base+1]=__expf(fminf(fmaxf(ch[1],-25.f),25.f));
                    out[base+2]=__expf(fminf(fmaxf(ch[2],-25.f),25.f));
                }
            }
        };

#pragma unroll 1
        for (int j=0;j<NITER;j++){
            if (j>=3){
                const int pr = j-3;          // quad index
                const int p  = pr&1;
                const float4 pv = x4Xv[p][sp][lane];
                const float  pw = x4Xw[p][sp][lane];
                post_step(pv, pw, 4*pr+sp);
            }
            pipe_barrier();
        }
    }
}

// ---------------------------------------------------------------- launch
extern "C" void kernel_launch(void* const* d_in, const int* in_sizes, int n_in,
                              void* d_out, int out_size, void* d_ws, size_t ws_size,
                              hipStream_t stream)
{
    (void)in_sizes; (void)n_in; (void)out_size; (void)d_ws; (void)ws_size;
    const float* xlni  = (const float*)d_in[0];
    const float* imean = (const float*)d_in[1];
    const float* istd  = (const float*)d_in[2];
    const float* l1w = (const float*)d_in[3];
    const float* l1b = (const float*)d_in[4];
    const float* g1  = (const float*)d_in[5];
    const float* l2w = (const float*)d_in[6];
    const float* l2b = (const float*)d_in[7];
    const float* g2  = (const float*)d_in[8];
    const float* wih1=(const float*)d_in[9];
    const float* whh1=(const float*)d_in[10];
    const float* bih1=(const float*)d_in[11];
    const float* bhh1=(const float*)d_in[12];
    const float* g3  =(const float*)d_in[13];
    const float* b3n =(const float*)d_in[14];
    const float* wih2=(const float*)d_in[15];
    const float* whh2=(const float*)d_in[16];
    const float* bih2=(const float*)d_in[17];
    const float* bhh2=(const float*)d_in[18];
    const float* g4  =(const float*)d_in[19];
    const float* l3w =(const float*)d_in[20];
    const float* l3b =(const float*)d_in[21];
    const float* g5  =(const float*)d_in[22];
    const float* l4w =(const float*)d_in[23];
    const float* l4b =(const float*)d_in[24];
    const float* g6  =(const float*)d_in[25];
    const float* l5w =(const float*)d_in[26];
    const float* l5b =(const float*)d_in[27];
    const float* wfw =(const float*)d_in[28];
    const float* wfb =(const float*)d_in[29];
    const float* sfw =(const float*)d_in[30];
    const float* sfb =(const float*)d_in[31];
    const float* dfw =(const float*)d_in[32];
    const float* dfb =(const float*)d_in[33];

    k_all<<<NTL, 512, 0, stream>>>(
        xlni, imean, istd,
        l1w, l1b, g1, l2w, l2b, g2,
        wih1, whh1, bih1, bhh1, g3, b3n,
        wih2, whh2, bih2, bhh2,
        g4, l3w, l3b, g5, l4w, l4b, g6, l5w, l5b,
        wfw, wfb, sfw, sfb, dfw, dfb,
        (float*)d_out);
}